// Round 13
// baseline (355.596 us; speedup 1.0000x reference)
//
#include <hip/hip_runtime.h>
#include <math.h>

#define HWSZ (512*512)
#define EPSV 1e-5f

typedef _Float16 h8 __attribute__((ext_vector_type(8)));
typedef _Float16 h4 __attribute__((ext_vector_type(4)));
typedef _Float16 h2 __attribute__((ext_vector_type(2)));
typedef float    f32x4 __attribute__((ext_vector_type(4)));

__device__ __forceinline__ h8 as_h8(uint4 u) { return __builtin_bit_cast(h8, u); }
__device__ __forceinline__ uint4 as_u4(h8 v) { return __builtin_bit_cast(uint4, v); }

// ---------------------------------------------------------------------------
// NCHW fp32 -> HWC fp16. 64 px x 64 ch tile via LDS; packed u32 stores.
// ---------------------------------------------------------------------------
__global__ __launch_bounds__(256) void to_hwc_f16(const float* __restrict__ in,
                                                  unsigned* __restrict__ out32) {
    __shared__ float T[64 * 65];
    int tid = threadIdx.x;
    int pbase = blockIdx.x * 64;
    int p = tid & 63, cg = tid >> 6;
#pragma unroll
    for (int j = 0; j < 16; ++j) {
        int c = cg * 16 + j;
        T[p * 65 + c] = in[c * HWSZ + pbase + p];
    }
    __syncthreads();
    int px = tid >> 2, cb = (tid & 3) * 16;
#pragma unroll
    for (int j = 0; j < 8; ++j) {
        int c = cb + 2 * j;
        h2 v = {(_Float16)T[px * 65 + c], (_Float16)T[px * 65 + c + 1]};
        out32[(pbase + px) * 32 + (c >> 1)] = __builtin_bit_cast(unsigned, v);
    }
}

// ---------------------------------------------------------------------------
// Weight prep. dcn: [o][c][3][3] -> [k][slice(8)][o][8ch] fp16 (r9 layout).
// off: [18][c][3][3] -> [k][o=32 pad][c] (for the fused in-dcn offset conv).
// ---------------------------------------------------------------------------
__global__ __launch_bounds__(256) void prep_all(
        const float* __restrict__ dw1, const float* __restrict__ dw2,
        const float* __restrict__ ow1, const float* __restrict__ ow2,
        _Float16* __restrict__ wT1, _Float16* __restrict__ wT2,
        _Float16* __restrict__ wTo1, _Float16* __restrict__ wTo2) {
    int i = blockIdx.x * 256 + threadIdx.x;
    if (i < 36864) {
        int k = i / 4096, r = i % 4096;
        int s = r >> 9, o = (r >> 3) & 63, j = r & 7;
        int c = (s >> 2) * 32 + (s & 3) * 8 + j;
        wT1[i] = (_Float16)dw1[(o * 64 + c) * 9 + k];
    } else if (i < 73728) {
        int ii = i - 36864;
        int k = ii / 4096, r = ii % 4096;
        int s = r >> 9, o = (r >> 3) & 63, j = r & 7;
        int c = (s >> 2) * 32 + (s & 3) * 8 + j;
        wT2[ii] = (_Float16)dw2[(o * 64 + c) * 9 + k];
    } else if (i < 92160) {
        int j = i - 73728;
        int k = j / 2048, r = j % 2048, o = r >> 6, c = r & 63;
        wTo1[k * 2048 + o * 64 + c] = (_Float16)((o < 18) ? ow1[(o * 64 + c) * 9 + k] : 0.f);
    } else if (i < 110592) {
        int j = i - 92160;
        int k = j / 2048, r = j % 2048, o = r >> 6, c = r & 63;
        wTo2[k * 2048 + o * 64 + c] = (_Float16)((o < 18) ? ow2[(o * 64 + c) * 9 + k] : 0.f);
    }
}

// ---------------------------------------------------------------------------
// Fused: offset-conv 3x3 (64->18) + deformable conv 3x3 (64->64) + bias +
// BN + ReLU, all from ONE 14x14 LDS window per 8x8 output tile.
// r13: the offset conv's 10x10 input neighborhood is a subset of dcn's
// 14x14 WIN, so the standalone conv3x3_off dispatch (~55us x2 + off[]
// global round-trip + 3x66 re-staging) is folded in: 36 extra MFMAs/wave
// reading the same WIN granules -> OFFB (2.5KB LDS) -> meta phase.
// Main deform loop unchanged from r12 (the verified 61us structure).
// ---------------------------------------------------------------------------
__global__ __launch_bounds__(256, 4) void dcn_fused(
        const _Float16* __restrict__ in, const _Float16* __restrict__ wTo,
        const float* __restrict__ off_bias,
        const _Float16* __restrict__ wTd, const float* __restrict__ bias,
        const float* __restrict__ gamma, const float* __restrict__ beta,
        const float* __restrict__ mean, const float* __restrict__ var,
        _Float16* __restrict__ out) {
    __shared__ uint4    WIN[196 * 8];    // 25.1 KB: 14x14 px window, swizzled
    __shared__ h4       SW9[9 * 64];     // 4.6 KB bilinear weights
    __shared__ short4   SI9[9 * 64];     // 4.6 KB window-relative corner coords
    __shared__ _Float16 OFFB[64][20];    // 2.5 KB: per-pixel 18 offset values
    __shared__ float    scl_s[64], sh_s[64];

    int tid = threadIdx.x;
    int bid = blockIdx.x;
    int ty = bid >> 6, tx = bid & 63;        // 64x64 tiles of 8x8 px
    int r0 = ty * 8, c0 = tx * 8;
    int wr0 = r0 - 3, wc0 = c0 - 3;          // window origin

    if (tid < 64) {
        float s = gamma[tid] * rsqrtf(var[tid] + EPSV);
        scl_s[tid] = s;
        sh_s[tid] = beta[tid] - mean[tid] * s + bias[tid] * s;
    }

    // ---- stage 14x14 window: 196 px x 8 slots(16B) = 1568 tasks, 7 rounds
    uint4 sv[7];
#pragma unroll
    for (int i = 0; i < 7; ++i) {
        int t = tid + 256 * i;
        int wp = t >> 3, cc = t & 7;
        int wi = wp / 14, wj = wp - wi * 14;
        int sy = wr0 + wi, sx = wc0 + wj;
        bool ok = (t < 1568) && ((unsigned)sy < 512u) && ((unsigned)sx < 512u);
        sv[i] = ok ? *(const uint4*)(in + ((sy << 9) + sx) * 64 + cc * 8)
                   : make_uint4(0u, 0u, 0u, 0u);
    }
#pragma unroll
    for (int i = 0; i < 7; ++i) {
        int t = tid + 256 * i;
        if (t < 1568) {
            int wp = t >> 3, cc = t & 7;
            WIN[wp * 8 + (cc ^ (wp & 7))] = sv[i];
        }
    }
    __syncthreads();   // window ready

    int l = tid & 63, wv = tid >> 6;
    int lq = l & 15, quad = l >> 4;
    int pxl = wv * 16 + lq;           // this lane's local pixel (0..63)

    // ---- fused offset conv (3x3 pad1, 64->18) straight from WIN
    {
        int pr = pxl >> 3, pc = pxl & 7;
        int wpb = (pr + 3) * 14 + (pc + 3);
        f32x4 zero = {0.f, 0.f, 0.f, 0.f};
        f32x4 oacc[2]; oacc[0] = zero; oacc[1] = zero;
#pragma unroll
        for (int k = 0; k < 9; ++k) {
            int wp = wpb + (k / 3 - 1) * 14 + (k % 3 - 1);
            int sw = wp & 7;
            h8 alo = as_h8(WIN[wp * 8 + (quad ^ sw)]);
            h8 ahi = as_h8(WIN[wp * 8 + ((quad + 4) ^ sw)]);
            const _Float16* wk = wTo + k * 2048;
#pragma unroll
            for (int h = 0; h < 2; ++h) {
                h8 b0 = *(const h8*)(wk + (h * 16 + lq) * 64 + quad * 8);
                h8 b1 = *(const h8*)(wk + (h * 16 + lq) * 64 + 32 + quad * 8);
                oacc[h] = __builtin_amdgcn_mfma_f32_16x16x32_f16(alo, b0, oacc[h], 0, 0, 0);
                oacc[h] = __builtin_amdgcn_mfma_f32_16x16x32_f16(ahi, b1, oacc[h], 0, 0, 0);
            }
        }
#pragma unroll
        for (int h = 0; h < 2; ++h) {
            int oc = h * 16 + lq;
            if (oc < 18) {
                float bb = off_bias[oc];
#pragma unroll
                for (int reg = 0; reg < 4; ++reg)
                    OFFB[wv * 16 + quad * 4 + reg][oc] = (_Float16)(oacc[h][reg] + bb);
            }
        }
    }
    __syncthreads();   // offsets ready

    // ---- per-pixel bilinear meta for all 9 taps (reads OFFB, not global)
    for (int t = tid; t < 576; t += 256) {
        int p = t & 63, k = t >> 6;
        int pr = p >> 3, pc = p & 7;
        int y = r0 + pr, x = c0 + pc;
        h2 dv = *(const h2*)&OFFB[p][2 * k];
        float py = (float)(y + k / 3 - 1) + (float)dv[0];
        float px = (float)(x + k % 3 - 1) + (float)dv[1];
        float y0f = floorf(py), x0f = floorf(px);
        float wy = py - y0f, wx = px - x0f;
        int y0 = (int)y0f, x0 = (int)x0f;
        int y1 = y0 + 1, x1 = x0 + 1;
        float vy0 = ((unsigned)y0 < 512u) ? 1.f : 0.f;
        float vy1 = ((unsigned)y1 < 512u) ? 1.f : 0.f;
        float vx0 = ((unsigned)x0 < 512u) ? 1.f : 0.f;
        float vx1 = ((unsigned)x1 < 512u) ? 1.f : 0.f;
        SW9[t] = (h4){(_Float16)((1.f - wy) * (1.f - wx) * vy0 * vx0),
                      (_Float16)((1.f - wy) * wx * vy0 * vx1),
                      (_Float16)(wy * (1.f - wx) * vy1 * vx0),
                      (_Float16)(wy * wx * vy1 * vx1)};
        int y0c = min(max(y0, 0), 511), y1c = min(max(y1, 0), 511);
        int x0c = min(max(x0, 0), 511), x1c = min(max(x1, 0), 511);
        SI9[t] = make_short4((short)(y0c - wr0), (short)(x0c - wc0),
                             (short)(y1c - wr0), (short)(x1c - wc0));
    }
    __syncthreads();   // meta ready

    // corner fetch: LDS window hot path, global fallback for out-of-window
#define CORNER(LO, HI, WY, WX) do {                                           \
        int wy_ = (WY), wx_ = (WX);                                           \
        if ((unsigned)wy_ < 14u && (unsigned)wx_ < 14u) {                     \
            int wp_ = wy_ * 14 + wx_;                                         \
            int sw_ = wp_ & 7;                                                \
            LO = as_h8(WIN[wp_ * 8 + (quad ^ sw_)]);                          \
            HI = as_h8(WIN[wp_ * 8 + ((quad + 4) ^ sw_)]);                    \
        } else {                                                              \
            int iy_ = wy_ + wr0, ix_ = wx_ + wc0;                             \
            const _Float16* g_ = in + ((iy_ << 9) + ix_) * 64 + quad * 8;     \
            LO = *(const h8*)g_;                                              \
            HI = *(const h8*)(g_ + 32);                                       \
        }                                                                     \
    } while (0)

    f32x4 zero = {0.f, 0.f, 0.f, 0.f};
    f32x4 acc[4];
    acc[0] = zero; acc[1] = zero; acc[2] = zero; acc[3] = zero;

#pragma unroll
    for (int k = 0; k < 9; ++k) {
        // B-frags: [k][slice][o][8] layout -> quarter-wave 256B contiguous
        const _Float16* wk = wTd + k * 4096;
        h8 bl[4], bh[4];
#pragma unroll
        for (int nb = 0; nb < 4; ++nb) {
            bl[nb] = *(const h8*)(wk + (quad * 64 + nb * 16 + lq) * 8);
            bh[nb] = *(const h8*)(wk + ((quad + 4) * 64 + nb * 16 + lq) * 8);
        }
        short4 s = SI9[k * 64 + pxl];
        h4 w = SW9[k * 64 + pxl];
        h8 c0l, c0h, c1l, c1h, c2l, c2h, c3l, c3h;
        CORNER(c0l, c0h, (int)s.x, (int)s.y);
        CORNER(c1l, c1h, (int)s.x, (int)s.w);
        CORNER(c2l, c2h, (int)s.z, (int)s.y);
        CORNER(c3l, c3h, (int)s.z, (int)s.w);
        h8 alo = c0l * w[0] + c1l * w[1] + c2l * w[2] + c3l * w[3];
        h8 ahi = c0h * w[0] + c1h * w[1] + c2h * w[2] + c3h * w[3];
#pragma unroll
        for (int nb = 0; nb < 4; ++nb)
            acc[nb] = __builtin_amdgcn_mfma_f32_16x16x32_f16(alo, bl[nb], acc[nb], 0, 0, 0);
#pragma unroll
        for (int nb = 0; nb < 4; ++nb)
            acc[nb] = __builtin_amdgcn_mfma_f32_16x16x32_f16(ahi, bh[nb], acc[nb], 0, 0, 0);
    }
#undef CORNER

    // ---- epilogue: BN + ReLU + store. acc[nb][reg] -> local px =
    // wv*16 + quad*4 + reg, oc = nb*16+lq.
#pragma unroll
    for (int nb = 0; nb < 4; ++nb) {
        float sc = scl_s[nb * 16 + lq];
        float sh = sh_s[nb * 16 + lq];
#pragma unroll
        for (int reg = 0; reg < 4; ++reg) {
            int p_out = wv * 16 + quad * 4 + reg;
            int gp = (r0 + (p_out >> 3)) * 512 + c0 + (p_out & 7);
            out[gp * 64 + nb * 16 + lq] =
                (_Float16)fmaxf(fmaf(acc[nb][reg], sc, sh), 0.f);
        }
    }
}

// ---------------------------------------------------------------------------
// 1x1 conv 64->1 + bias (fp16 HWC in, fp32 out)
// ---------------------------------------------------------------------------
__global__ __launch_bounds__(256) void conv1x1_out(const _Float16* __restrict__ in,
                                                   const float* __restrict__ w,
                                                   const float* __restrict__ b,
                                                   float* __restrict__ out) {
    int p = blockIdx.x * 256 + threadIdx.x;
    float acc = b[0];
    const h8* ip = (const h8*)(in + p * 64);
#pragma unroll
    for (int j = 0; j < 8; ++j) {
        h8 v = ip[j];
#pragma unroll
        for (int e = 0; e < 8; ++e)
            acc = fmaf((float)v[e], w[j * 8 + e], acc);
    }
    out[p] = acc;
}

// ---------------------------------------------------------------------------
extern "C" void kernel_launch(void* const* d_in, const int* in_sizes, int n_in,
                              void* d_out, int out_size, void* d_ws, size_t ws_size,
                              hipStream_t stream) {
    const float* x      = (const float*)d_in[0];
    const float* off1_w = (const float*)d_in[1];
    const float* off1_b = (const float*)d_in[2];
    const float* dcn1_w = (const float*)d_in[3];
    const float* dcn1_b = (const float*)d_in[4];
    const float* bn1_g  = (const float*)d_in[5];
    const float* bn1_be = (const float*)d_in[6];
    const float* bn1_m  = (const float*)d_in[7];
    const float* bn1_v  = (const float*)d_in[8];
    const float* off2_w = (const float*)d_in[9];
    const float* off2_b = (const float*)d_in[10];
    const float* dcn2_w = (const float*)d_in[11];
    const float* dcn2_b = (const float*)d_in[12];
    const float* bn2_g  = (const float*)d_in[13];
    const float* bn2_be = (const float*)d_in[14];
    const float* bn2_m  = (const float*)d_in[15];
    const float* bn2_v  = (const float*)d_in[16];
    const float* conv_w = (const float*)d_in[17];
    const float* conv_b = (const float*)d_in[18];
    float* out = (float*)d_out;

    char* ws = (char*)d_ws;
    _Float16* xh   = (_Float16*)ws;                       // 32 MiB
    _Float16* h1   = (_Float16*)(ws + 33554432);          // 32 MiB
    _Float16* wT1  = (_Float16*)(ws + 2 * 33554432);
    _Float16* wT2  = wT1 + 36864;
    _Float16* wTo1 = wT2 + 36864;
    _Float16* wTo2 = wTo1 + 18432;
    _Float16* h2 = xh;

    prep_all<<<432, 256, 0, stream>>>(dcn1_w, dcn2_w, off1_w, off2_w,
                                      wT1, wT2, wTo1, wTo2);
    to_hwc_f16<<<4096, 256, 0, stream>>>(x, (unsigned*)xh);

    dcn_fused<<<4096, 256, 0, stream>>>(xh, wTo1, off1_b, wT1, dcn1_b,
                                        bn1_g, bn1_be, bn1_m, bn1_v, h1);
    dcn_fused<<<4096, 256, 0, stream>>>(h1, wTo2, off2_b, wT2, dcn2_b,
                                        bn2_g, bn2_be, bn2_m, bn2_v, h2);
    conv1x1_out<<<1024, 256, 0, stream>>>(h2, conv_w, conv_b, out);
}

// Round 14
// 282.913 us; speedup vs baseline: 1.2569x; 1.2569x over previous
//
#include <hip/hip_runtime.h>
#include <math.h>

#define HWSZ (512*512)
#define EPSV 1e-5f

typedef _Float16 h8 __attribute__((ext_vector_type(8)));
typedef _Float16 h4 __attribute__((ext_vector_type(4)));
typedef _Float16 h2 __attribute__((ext_vector_type(2)));
typedef float    f32x4 __attribute__((ext_vector_type(4)));

__device__ __forceinline__ h8 as_h8(uint4 u) { return __builtin_bit_cast(h8, u); }
__device__ __forceinline__ uint4 as_u4(h8 v) { return __builtin_bit_cast(uint4, v); }

// XCD-contiguous bijective remap (kept on conv3x3 only).
__device__ __forceinline__ int xcd_swz_4096(int bid) {
    return (bid & 7) * 512 + (bid >> 3);
}

// ---------------------------------------------------------------------------
// NCHW fp32 -> HWC fp16. 64 px x 64 ch tile via LDS; packed u32 stores.
// ---------------------------------------------------------------------------
__global__ __launch_bounds__(256) void to_hwc_f16(const float* __restrict__ in,
                                                  unsigned* __restrict__ out32) {
    __shared__ float T[64 * 65];
    int tid = threadIdx.x;
    int pbase = blockIdx.x * 64;
    int p = tid & 63, cg = tid >> 6;
#pragma unroll
    for (int j = 0; j < 16; ++j) {
        int c = cg * 16 + j;
        T[p * 65 + c] = in[c * HWSZ + pbase + p];
    }
    __syncthreads();
    int px = tid >> 2, cb = (tid & 3) * 16;
#pragma unroll
    for (int j = 0; j < 8; ++j) {
        int c = cb + 2 * j;
        h2 v = {(_Float16)T[px * 65 + c], (_Float16)T[px * 65 + c + 1]};
        out32[(pbase + px) * 32 + (c >> 1)] = __builtin_bit_cast(unsigned, v);
    }
}

// ---------------------------------------------------------------------------
// Weight prep. dcn: [o][c][3][3] -> [k][slice(8)][o=64][8ch] (512/slice).
// off: [18][c][3][3] -> [k][slice(8)][o=32 pad][8ch] (256/slice) — r14: same
// coalesced per-tap pattern that dcn validated at 61us.
// ---------------------------------------------------------------------------
__global__ __launch_bounds__(256) void prep_all(
        const float* __restrict__ dw1, const float* __restrict__ dw2,
        const float* __restrict__ ow1, const float* __restrict__ ow2,
        _Float16* __restrict__ wT1, _Float16* __restrict__ wT2,
        _Float16* __restrict__ wTo1, _Float16* __restrict__ wTo2) {
    int i = blockIdx.x * 256 + threadIdx.x;
    if (i < 36864) {
        int k = i / 4096, r = i % 4096;
        int s = r >> 9, o = (r >> 3) & 63, j = r & 7;
        int c = (s >> 2) * 32 + (s & 3) * 8 + j;
        wT1[i] = (_Float16)dw1[(o * 64 + c) * 9 + k];
    } else if (i < 73728) {
        int ii = i - 36864;
        int k = ii / 4096, r = ii % 4096;
        int s = r >> 9, o = (r >> 3) & 63, j = r & 7;
        int c = (s >> 2) * 32 + (s & 3) * 8 + j;
        wT2[ii] = (_Float16)dw2[(o * 64 + c) * 9 + k];
    } else if (i < 92160) {
        int jj = i - 73728;
        int k = jj / 2048, r = jj % 2048;
        int s = r >> 8, o = (r >> 3) & 31, j = r & 7;
        int c = (s >> 2) * 32 + (s & 3) * 8 + j;
        wTo1[jj] = (_Float16)((o < 18) ? ow1[(o * 64 + c) * 9 + k] : 0.f);
    } else if (i < 110592) {
        int jj = i - 92160;
        int k = jj / 2048, r = jj % 2048;
        int s = r >> 8, o = (r >> 3) & 31, j = r & 7;
        int c = (s >> 2) * 32 + (s & 3) * 8 + j;
        wTo2[jj] = (_Float16)((o < 18) ? ow2[(o * 64 + c) * 9 + k] : 0.f);
    }
}

// ---------------------------------------------------------------------------
// 3x3 conv 64->18 (pad 32) via MFMA.
// r14: breg[18] hoist (72 resident VGPRs -> VGPR-bound 4 blocks/CU) replaced
// by per-tap coalesced B loads from the [k][slice][o][8] table (256B per
// quarter-wave, L1-hot 18KB) — the exact pattern dcn runs at 61us with
// VGPR=52. Frees registers -> LDS-bound 6 blocks/CU (75% occ).
// ---------------------------------------------------------------------------
__global__ __launch_bounds__(256, 4) void conv3x3_off_mfma(
        const _Float16* __restrict__ in, const _Float16* __restrict__ wTo,
        const float* __restrict__ bias, _Float16* __restrict__ off) {
    __shared__ uint4 TILE[3 * 66 * 8];   // 25.3 KB

    int tid = threadIdx.x;
    int pbase = xcd_swz_4096(blockIdx.x) * 64;
    int y = pbase >> 9, xblk = pbase & 511;
    int l = tid & 63, wv = tid >> 6;
    int lq = l & 15, quad = l >> 4;
    int wn = wv & 1, wm = wv >> 1;     // wave tile: 32 px x 16 n

    // stage: 1584 16B tasks, batched into 7 independent predicated loads
    uint4 v[7];
#pragma unroll
    for (int i = 0; i < 7; ++i) {
        int t = tid + 256 * i;
        int row = t / 528, r = t - row * 528;
        int col = r >> 3, cc = r & 7;
        int sy = y + row - 1, sx = xblk + col - 1;
        bool ok = (t < 1584) && ((unsigned)sy < 512u) && ((unsigned)sx < 512u);
        v[i] = ok ? *(const uint4*)(in + (sy * 512 + sx) * 64 + cc * 8)
                  : make_uint4(0u, 0u, 0u, 0u);
    }
#pragma unroll
    for (int i = 0; i < 7; ++i) {
        int t = tid + 256 * i;
        if (t < 1584) {
            int row = t / 528, r = t - row * 528;
            int col = r >> 3, cc = r & 7;
            TILE[(row * 66 + col) * 8 + (cc ^ (col & 7))] = v[i];
        }
    }
    __syncthreads();

    f32x4 zero = {0.f, 0.f, 0.f, 0.f};
    f32x4 acc[2]; acc[0] = zero; acc[1] = zero;

#pragma unroll
    for (int k = 0; k < 9; ++k) {
        int ky = k / 3, kx = k % 3;
#pragma unroll
        for (int kc = 0; kc < 2; ++kc) {
            // B frag for cols n=wn*16+lq, k-chunk kc: slice s = kc*4+quad
            h8 b = *(const h8*)(wTo + k * 2048 + (kc * 4 + quad) * 256
                                + (wn * 16 + lq) * 8);
#pragma unroll
            for (int tm = 0; tm < 2; ++tm) {
                int col = kx + wm * 32 + tm * 16 + lq;
                int cc0 = kc * 4 + quad;
                h8 a = as_h8(TILE[(ky * 66 + col) * 8 + (cc0 ^ (col & 7))]);
                acc[tm] = __builtin_amdgcn_mfma_f32_16x16x32_f16(a, b, acc[tm], 0, 0, 0);
            }
        }
    }

    int n = wn * 16 + lq;
    if (n < 18) {
        float bb = bias[n];
#pragma unroll
        for (int tm = 0; tm < 2; ++tm)
#pragma unroll
            for (int reg = 0; reg < 4; ++reg) {
                int px = wm * 32 + tm * 16 + quad * 4 + reg;
                off[(pbase + px) * 18 + n] = (_Float16)(acc[tm][reg] + bb);
            }
    }
}

// ---------------------------------------------------------------------------
// Deformable conv 3x3 64->64 + bias + BN + ReLU via f16 MFMA.
// EXACT r12 structure (verified 61us): 8x8 tile, 14x14 LDS window (XOR slot
// swizzle), wave-local blend -> A-frags, per-tap coalesced B-loads, zero
// barriers in the tap loop, launch_bounds(256,4).
// ---------------------------------------------------------------------------
__global__ __launch_bounds__(256, 4) void dcn_fused(
        const _Float16* __restrict__ in, const _Float16* __restrict__ off,
        const _Float16* __restrict__ wTd, const float* __restrict__ bias,
        const float* __restrict__ gamma, const float* __restrict__ beta,
        const float* __restrict__ mean, const float* __restrict__ var,
        _Float16* __restrict__ out) {
    __shared__ uint4  WIN[196 * 8];    // 25.1 KB: 14x14 px window, swizzled
    __shared__ h4     SW9[9 * 64];     // 4.6 KB bilinear weights
    __shared__ short4 SI9[9 * 64];     // 4.6 KB window-relative corner coords
    __shared__ float  scl_s[64], sh_s[64];

    int tid = threadIdx.x;
    int bid = blockIdx.x;
    int ty = bid >> 6, tx = bid & 63;        // 64x64 tiles of 8x8 px
    int r0 = ty * 8, c0 = tx * 8;
    int wr0 = r0 - 3, wc0 = c0 - 3;          // window origin

    // ---- per-pixel bilinear meta for all 9 taps (window-relative coords)
    for (int t = tid; t < 576; t += 256) {
        int p = t & 63, k = t >> 6;
        int pr = p >> 3, pc = p & 7;
        int y = r0 + pr, x = c0 + pc;
        int gp = y * 512 + x;
        h2 dv = *(const h2*)(off + gp * 18 + 2 * k);
        float py = (float)(y + k / 3 - 1) + (float)dv[0];
        float px = (float)(x + k % 3 - 1) + (float)dv[1];
        float y0f = floorf(py), x0f = floorf(px);
        float wy = py - y0f, wx = px - x0f;
        int y0 = (int)y0f, x0 = (int)x0f;
        int y1 = y0 + 1, x1 = x0 + 1;
        float vy0 = ((unsigned)y0 < 512u) ? 1.f : 0.f;
        float vy1 = ((unsigned)y1 < 512u) ? 1.f : 0.f;
        float vx0 = ((unsigned)x0 < 512u) ? 1.f : 0.f;
        float vx1 = ((unsigned)x1 < 512u) ? 1.f : 0.f;
        SW9[t] = (h4){(_Float16)((1.f - wy) * (1.f - wx) * vy0 * vx0),
                      (_Float16)((1.f - wy) * wx * vy0 * vx1),
                      (_Float16)(wy * (1.f - wx) * vy1 * vx0),
                      (_Float16)(wy * wx * vy1 * vx1)};
        int y0c = min(max(y0, 0), 511), y1c = min(max(y1, 0), 511);
        int x0c = min(max(x0, 0), 511), x1c = min(max(x1, 0), 511);
        SI9[t] = make_short4((short)(y0c - wr0), (short)(x0c - wc0),
                             (short)(y1c - wr0), (short)(x1c - wc0));
    }
    if (tid < 64) {
        float s = gamma[tid] * rsqrtf(var[tid] + EPSV);
        scl_s[tid] = s;
        sh_s[tid] = beta[tid] - mean[tid] * s + bias[tid] * s;
    }

    // ---- stage 14x14 window: 196 px x 8 slots(16B) = 1568 tasks, 7 rounds
    uint4 sv[7];
#pragma unroll
    for (int i = 0; i < 7; ++i) {
        int t = tid + 256 * i;
        int wp = t >> 3, cc = t & 7;
        int wi = wp / 14, wj = wp - wi * 14;
        int sy = wr0 + wi, sx = wc0 + wj;
        bool ok = (t < 1568) && ((unsigned)sy < 512u) && ((unsigned)sx < 512u);
        sv[i] = ok ? *(const uint4*)(in + ((sy << 9) + sx) * 64 + cc * 8)
                   : make_uint4(0u, 0u, 0u, 0u);
    }
#pragma unroll
    for (int i = 0; i < 7; ++i) {
        int t = tid + 256 * i;
        if (t < 1568) {
            int wp = t >> 3, cc = t & 7;
            WIN[wp * 8 + (cc ^ (wp & 7))] = sv[i];
        }
    }
    __syncthreads();   // window + meta ready (the only barrier)

    int l = tid & 63, wv = tid >> 6;
    int lq = l & 15, quad = l >> 4;
    int pxl = wv * 16 + lq;           // this lane's local pixel (0..63)

    // corner fetch: LDS window hot path, global fallback for out-of-window
#define CORNER(LO, HI, WY, WX) do {                                           \
        int wy_ = (WY), wx_ = (WX);                                           \
        if ((unsigned)wy_ < 14u && (unsigned)wx_ < 14u) {                     \
            int wp_ = wy_ * 14 + wx_;                                         \
            int sw_ = wp_ & 7;                                                \
            LO = as_h8(WIN[wp_ * 8 + (quad ^ sw_)]);                          \
            HI = as_h8(WIN[wp_ * 8 + ((quad + 4) ^ sw_)]);                    \
        } else {                                                              \
            int iy_ = wy_ + wr0, ix_ = wx_ + wc0;                             \
            const _Float16* g_ = in + ((iy_ << 9) + ix_) * 64 + quad * 8;     \
            LO = *(const h8*)g_;                                              \
            HI = *(const h8*)(g_ + 32);                                       \
        }                                                                     \
    } while (0)

    f32x4 zero = {0.f, 0.f, 0.f, 0.f};
    f32x4 acc[4];
    acc[0] = zero; acc[1] = zero; acc[2] = zero; acc[3] = zero;

#pragma unroll
    for (int k = 0; k < 9; ++k) {
        // B-frags: [k][slice][o][8] layout -> quarter-wave 256B contiguous
        const _Float16* wk = wTd + k * 4096;
        h8 bl[4], bh[4];
#pragma unroll
        for (int nb = 0; nb < 4; ++nb) {
            bl[nb] = *(const h8*)(wk + (quad * 64 + nb * 16 + lq) * 8);
            bh[nb] = *(const h8*)(wk + ((quad + 4) * 64 + nb * 16 + lq) * 8);
        }
        short4 s = SI9[k * 64 + pxl];
        h4 w = SW9[k * 64 + pxl];
        h8 c0l, c0h, c1l, c1h, c2l, c2h, c3l, c3h;
        CORNER(c0l, c0h, (int)s.x, (int)s.y);
        CORNER(c1l, c1h, (int)s.x, (int)s.w);
        CORNER(c2l, c2h, (int)s.z, (int)s.y);
        CORNER(c3l, c3h, (int)s.z, (int)s.w);
        h8 alo = c0l * w[0] + c1l * w[1] + c2l * w[2] + c3l * w[3];
        h8 ahi = c0h * w[0] + c1h * w[1] + c2h * w[2] + c3h * w[3];
#pragma unroll
        for (int nb = 0; nb < 4; ++nb)
            acc[nb] = __builtin_amdgcn_mfma_f32_16x16x32_f16(alo, bl[nb], acc[nb], 0, 0, 0);
#pragma unroll
        for (int nb = 0; nb < 4; ++nb)
            acc[nb] = __builtin_amdgcn_mfma_f32_16x16x32_f16(ahi, bh[nb], acc[nb], 0, 0, 0);
    }
#undef CORNER

    // ---- epilogue: BN + ReLU + store. acc[nb][reg] -> local px =
    // wv*16 + quad*4 + reg, oc = nb*16+lq.
#pragma unroll
    for (int nb = 0; nb < 4; ++nb) {
        float sc = scl_s[nb * 16 + lq];
        float sh = sh_s[nb * 16 + lq];
#pragma unroll
        for (int reg = 0; reg < 4; ++reg) {
            int p_out = wv * 16 + quad * 4 + reg;
            int gp = (r0 + (p_out >> 3)) * 512 + c0 + (p_out & 7);
            out[gp * 64 + nb * 16 + lq] =
                (_Float16)fmaxf(fmaf(acc[nb][reg], sc, sh), 0.f);
        }
    }
}

// ---------------------------------------------------------------------------
// 1x1 conv 64->1 + bias (fp16 HWC in, fp32 out)
// ---------------------------------------------------------------------------
__global__ __launch_bounds__(256) void conv1x1_out(const _Float16* __restrict__ in,
                                                   const float* __restrict__ w,
                                                   const float* __restrict__ b,
                                                   float* __restrict__ out) {
    int p = blockIdx.x * 256 + threadIdx.x;
    float acc = b[0];
    const h8* ip = (const h8*)(in + p * 64);
#pragma unroll
    for (int j = 0; j < 8; ++j) {
        h8 v = ip[j];
#pragma unroll
        for (int e = 0; e < 8; ++e)
            acc = fmaf((float)v[e], w[j * 8 + e], acc);
    }
    out[p] = acc;
}

// ---------------------------------------------------------------------------
extern "C" void kernel_launch(void* const* d_in, const int* in_sizes, int n_in,
                              void* d_out, int out_size, void* d_ws, size_t ws_size,
                              hipStream_t stream) {
    const float* x      = (const float*)d_in[0];
    const float* off1_w = (const float*)d_in[1];
    const float* off1_b = (const float*)d_in[2];
    const float* dcn1_w = (const float*)d_in[3];
    const float* dcn1_b = (const float*)d_in[4];
    const float* bn1_g  = (const float*)d_in[5];
    const float* bn1_be = (const float*)d_in[6];
    const float* bn1_m  = (const float*)d_in[7];
    const float* bn1_v  = (const float*)d_in[8];
    const float* off2_w = (const float*)d_in[9];
    const float* off2_b = (const float*)d_in[10];
    const float* dcn2_w = (const float*)d_in[11];
    const float* dcn2_b = (const float*)d_in[12];
    const float* bn2_g  = (const float*)d_in[13];
    const float* bn2_be = (const float*)d_in[14];
    const float* bn2_m  = (const float*)d_in[15];
    const float* bn2_v  = (const float*)d_in[16];
    const float* conv_w = (const float*)d_in[17];
    const float* conv_b = (const float*)d_in[18];
    float* out = (float*)d_out;

    char* ws = (char*)d_ws;
    _Float16* xh   = (_Float16*)ws;                       // 32 MiB
    _Float16* h1   = (_Float16*)(ws + 33554432);          // 32 MiB
    _Float16* offb = (_Float16*)(ws + 2 * 33554432);      // 9 MiB
    _Float16* wT1  = (_Float16*)(ws + 2 * 33554432 + 9437184);
    _Float16* wT2  = wT1 + 36864;
    _Float16* wTo1 = wT2 + 36864;
    _Float16* wTo2 = wTo1 + 18432;
    _Float16* h2 = xh;

    prep_all<<<432, 256, 0, stream>>>(dcn1_w, dcn2_w, off1_w, off2_w,
                                      wT1, wT2, wTo1, wTo2);
    to_hwc_f16<<<4096, 256, 0, stream>>>(x, (unsigned*)xh);

    conv3x3_off_mfma<<<4096, 256, 0, stream>>>(xh, wTo1, off1_b, offb);
    dcn_fused<<<4096, 256, 0, stream>>>(xh, offb, wT1, dcn1_b,
                                        bn1_g, bn1_be, bn1_m, bn1_v, h1);
    conv3x3_off_mfma<<<4096, 256, 0, stream>>>(h1, wTo2, off2_b, offb);
    dcn_fused<<<4096, 256, 0, stream>>>(h1, offb, wT2, dcn2_b,
                                        bn2_g, bn2_be, bn2_m, bn2_v, h2);
    conv1x1_out<<<1024, 256, 0, stream>>>(h2, conv_w, conv_b, out);
}